// Round 1
// baseline (391.057 us; speedup 1.0000x reference)
//
#include <hip/hip_runtime.h>

typedef short bf16x8 __attribute__((ext_vector_type(8)));
typedef float f32x4 __attribute__((ext_vector_type(4)));
typedef unsigned int u32;
typedef unsigned long long u64;

#define GLD_LDS16(gp, lp) \
  __builtin_amdgcn_global_load_lds((const __attribute__((address_space(1))) u32*)(gp), \
                                   (__attribute__((address_space(3))) u32*)(lp), 16, 0, 0)

__device__ __forceinline__ short f2bf(float f) {
  u32 u = __builtin_bit_cast(u32, f);
  u = (u + 0x7fffu + ((u >> 16) & 1u)) >> 16;
  return (short)u;
}

// ---------------- small prep kernels ----------------

__global__ void cvt_f32_bf16(const float* __restrict__ in, short* __restrict__ out, int n4) {
  int i = (blockIdx.x * 256 + threadIdx.x) * 4;
  float4 v = *(const float4*)(in + i);
  short4 o;
  o.x = f2bf(v.x); o.y = f2bf(v.y); o.z = f2bf(v.z); o.w = f2bf(v.w);
  *(short4*)(out + i) = o;
}

__global__ void rope_tables(const float* __restrict__ rpe, float* __restrict__ cosT,
                            float* __restrict__ sinT) {
  int i = blockIdx.x * 256 + threadIdx.x;  // 32768 = 1024*32
  float v = rpe[i];
  cosT[i] = cosf(v);
  sinT[i] = sinf(v);
}

__global__ void mask_pack(const int* __restrict__ m, u64* __restrict__ out) {
  int i = blockIdx.x * 256 + threadIdx.x;  // 8*1024*1024 threads
  u64 bm = __ballot(m[i] != 0);
  if ((threadIdx.x & 63) == 0) out[i >> 6] = bm;
}

// ---------------- GEMM 1: QKV projection + bias + RoPE + scatter ----------------
// X (8192,1024) bf16, W (3072,1024) bf16; C = X * W^T. Tile 128x128, BK=32.
__global__ __launch_bounds__(256, 2) void gemm_qkv(
    const short* __restrict__ Xb, const short* __restrict__ Wb,
    const float* __restrict__ bqkv, const float* __restrict__ cosT,
    const float* __restrict__ sinT, short* __restrict__ qb,
    short* __restrict__ kbuf, short* __restrict__ vbuf) {
  __shared__ short Ash[128 * 32];
  __shared__ short Bsh[128 * 32];
  const int tid = threadIdx.x;
  const int wid = tid >> 6, lane = tid & 63;
  const int g = lane >> 4, c = lane & 15;
  const int wm = wid >> 1, wn = wid & 1;
  const int m0 = blockIdx.y * 128, n0 = blockIdx.x * 128;

  f32x4 acc[4][4];
  for (int i = 0; i < 4; i++)
    for (int j = 0; j < 4; j++) acc[i][j] = (f32x4){0.f, 0.f, 0.f, 0.f};

  const int srow = lane >> 2;
  const int scol = (lane & 3) * 8;
  const short* AgL = Xb + (long)(m0 + wid * 32 + srow) * 1024 + scol;
  const short* BgL = Wb + (long)(n0 + wid * 32 + srow) * 1024 + scol;
  short* As0 = &Ash[(wid * 32) * 32];
  short* As1 = &Ash[(wid * 32 + 16) * 32];
  short* Bs0 = &Bsh[(wid * 32) * 32];
  short* Bs1 = &Bsh[(wid * 32 + 16) * 32];

  for (int kt = 0; kt < 32; ++kt) {
    const int ko = kt * 32;
    GLD_LDS16(AgL + ko, As0);
    GLD_LDS16(AgL + ko + 16 * 1024, As1);
    GLD_LDS16(BgL + ko, Bs0);
    GLD_LDS16(BgL + ko + 16 * 1024, Bs1);
    __syncthreads();
    bf16x8 af[4], bfr[4];
    for (int i = 0; i < 4; i++)
      af[i] = *(const bf16x8*)&Ash[(wm * 64 + i * 16 + c) * 32 + g * 8];
    for (int j = 0; j < 4; j++)
      bfr[j] = *(const bf16x8*)&Bsh[(wn * 64 + j * 16 + c) * 32 + g * 8];
    for (int i = 0; i < 4; i++)
      for (int j = 0; j < 4; j++)
        acc[i][j] = __builtin_amdgcn_mfma_f32_16x16x32_bf16(af[i], bfr[j], acc[i][j], 0, 0, 0);
    __syncthreads();
  }

  // epilogue: bias, RoPE (q,k), scatter to (B,H,L,D); q pre-scaled by 0.125
  for (int jt = 0; jt < 4; jt++) {
    const int j = n0 + wn * 64 + jt * 16 + c;
    const int three = j >> 10;
    const int hh = (j >> 6) & 15;
    const int d = j & 63;
    const float bias = bqkv[j];
    for (int i = 0; i < 4; i++) {
      const int rbase = m0 + wm * 64 + i * 16 + g * 4;
      for (int reg = 0; reg < 4; reg++) {
        const int r = rbase + reg;
        const int l = r >> 3, b = r & 7;
        float v = acc[i][jt][reg] + bias;
        if (three == 2) {
          vbuf[((long)(b * 16 + hh) * 1024 + l) * 64 + d] = f2bf(v);
        } else {
          float part = __shfl_xor(v, 1, 64);
          float cs = cosT[l * 32 + (d & 31)];
          float sn = sinT[l * 32 + (d & 31)];
          float res = v * cs + ((d & 1) ? part : -part) * sn;
          if (three == 0) res *= 0.125f;  // fold 1/sqrt(D) into q
          short* dst = (three == 0) ? qb : kbuf;
          dst[((long)(b * 16 + hh) * 1024 + l) * 64 + d] = f2bf(res);
        }
      }
    }
  }
}

// ---------------- V transpose: (B,H,L,D) -> (B,H,D,L) ----------------
__global__ __launch_bounds__(256) void transpose_v(const short* __restrict__ vbuf,
                                                   short* __restrict__ vTb) {
  __shared__ short T[64 * 72];
  const int bh = blockIdx.y;
  const int l0 = blockIdx.x * 64;
  const int t = threadIdx.x;
  const int row = t >> 3;
  const int cc = (t & 7) * 8;
  const short* src = vbuf + ((long)bh * 1024 + l0) * 64;
  for (int p = 0; p < 2; p++) {
    int lr = row + p * 32;
    *(bf16x8*)&T[lr * 72 + cc] = *(const bf16x8*)&src[(long)lr * 64 + cc];
  }
  __syncthreads();
  short* dst = vTb + (long)bh * 64 * 1024 + l0;
  for (int p = 0; p < 2; p++) {
    int d = row + p * 32;
    bf16x8 v;
    for (int j = 0; j < 8; j++) v[j] = T[(cc + j) * 72 + d];
    *(bf16x8*)&dst[(long)d * 1024 + cc] = v;
  }
}

// ---------------- flash attention ----------------
// q,k: (BH,1024,64) bf16 (q pre-scaled); vT: (BH,64,1024) bf16; maskb: bits (B,1024,16 u64)
__global__ __launch_bounds__(256, 2) void flash_attn(
    const short* __restrict__ qb, const short* __restrict__ kbuf,
    const short* __restrict__ vTb, const u64* __restrict__ maskb,
    short* __restrict__ attno) {
  __shared__ short Ksh[64 * 72];
  __shared__ short Vsh[64 * 72];
  __shared__ short Psh[4 * 16 * 72];
  const int t = threadIdx.x;
  const int wid = t >> 6, lane = t & 63;
  const int g = lane >> 4, c = lane & 15;
  const int q0 = blockIdx.x * 64;
  const int bh = blockIdx.y;
  const int b = bh >> 4;
  const long qoff = (long)bh * 1024 * 64;

  bf16x8 aq0, aq1;
  {
    const short* qrow = qb + qoff + (long)(q0 + wid * 16 + c) * 64;
    aq0 = *(const bf16x8*)(qrow + g * 8);
    aq1 = *(const bf16x8*)(qrow + 32 + g * 8);
  }
  f32x4 O[4];
  for (int i = 0; i < 4; i++) O[i] = (f32x4){0.f, 0.f, 0.f, 0.f};
  float m_run[4], l_run[4];
  for (int r = 0; r < 4; r++) { m_run[r] = -1e30f; l_run[r] = 0.f; }

  const u64* mrow[4];
  for (int r = 0; r < 4; r++)
    mrow[r] = maskb + ((long)b * 1024 + q0 + wid * 16 + g * 4 + r) * 16;

  const short* Kg = kbuf + qoff;
  const short* Vg = vTb + qoff;
  const int srow = t >> 3;
  const int swz = ((t & 7) ^ (srow & 7)) * 8;  // xor-swizzled 16B chunk to spread LDS banks

  for (int ki = 0; ki < 16; ++ki) {
    const int kt0 = ki * 64;
    __syncthreads();
    for (int p = 0; p < 2; p++) {
      int rr = srow + p * 32;
      int sw = ((t & 7) ^ (rr & 7)) * 8;
      *(bf16x8*)&Ksh[rr * 72 + sw] = *(const bf16x8*)&Kg[(long)(kt0 + rr) * 64 + sw];
      *(bf16x8*)&Vsh[rr * 72 + sw] = *(const bf16x8*)&Vg[(long)rr * 1024 + kt0 + sw];
    }
    __syncthreads();

    f32x4 S[4];
    for (int nt = 0; nt < 4; nt++) {
      const short* kr = &Ksh[(nt * 16 + c) * 72 + g * 8];
      bf16x8 bk0 = *(const bf16x8*)kr;
      bf16x8 bk1 = *(const bf16x8*)(kr + 32);
      f32x4 z = (f32x4){0.f, 0.f, 0.f, 0.f};
      z = __builtin_amdgcn_mfma_f32_16x16x32_bf16(aq0, bk0, z, 0, 0, 0);
      z = __builtin_amdgcn_mfma_f32_16x16x32_bf16(aq1, bk1, z, 0, 0, 0);
      S[nt] = z;
    }

    u64 mw[4];
    for (int r = 0; r < 4; r++) mw[r] = mrow[r][ki];
    float alpha[4];
    for (int r = 0; r < 4; r++) {
      float sv[4];
      float mx = -1e30f;
      for (int nt = 0; nt < 4; nt++) {
        bool on = (mw[r] >> (nt * 16 + c)) & 1ull;
        float s = on ? S[nt][r] : -1e30f;
        sv[nt] = s;
        mx = fmaxf(mx, s);
      }
      for (int off = 1; off < 16; off <<= 1) mx = fmaxf(mx, __shfl_xor(mx, off, 64));
      float mnew = fmaxf(m_run[r], mx);
      float al = __expf(m_run[r] - mnew);
      float rs = 0.f;
      for (int nt = 0; nt < 4; nt++) {
        float p = (sv[nt] > -0.9e30f) ? __expf(sv[nt] - mnew) : 0.f;
        rs += p;
        Psh[(wid * 16 + g * 4 + r) * 72 + nt * 16 + c] = f2bf(p);
      }
      for (int off = 1; off < 16; off <<= 1) rs += __shfl_xor(rs, off, 64);
      l_run[r] = l_run[r] * al + rs;
      m_run[r] = mnew;
      alpha[r] = al;
    }
    for (int nt = 0; nt < 4; nt++)
      for (int r = 0; r < 4; r++) O[nt][r] *= alpha[r];
    __asm__ volatile("s_waitcnt lgkmcnt(0)" ::: "memory");

    bf16x8 ap0 = *(const bf16x8*)&Psh[(wid * 16 + c) * 72 + g * 8];
    bf16x8 ap1 = *(const bf16x8*)&Psh[(wid * 16 + c) * 72 + 32 + g * 8];
    for (int nt = 0; nt < 4; nt++) {
      const short* vr = &Vsh[(nt * 16 + c) * 72 + g * 8];
      bf16x8 bv0 = *(const bf16x8*)vr;
      bf16x8 bv1 = *(const bf16x8*)(vr + 32);
      O[nt] = __builtin_amdgcn_mfma_f32_16x16x32_bf16(ap0, bv0, O[nt], 0, 0, 0);
      O[nt] = __builtin_amdgcn_mfma_f32_16x16x32_bf16(ap1, bv1, O[nt], 0, 0, 0);
    }
  }

  const int h = bh & 15;
  for (int r = 0; r < 4; r++) {
    float inv = 1.f / l_run[r];
    int lrow = q0 + wid * 16 + g * 4 + r;
    long rbase = ((long)lrow * 8 + b) * 1024 + h * 64;
    for (int nt = 0; nt < 4; nt++)
      attno[rbase + nt * 16 + c] = f2bf(O[nt][r] * inv);
  }
}

// Wait: K/V staging uses swizzled chunks but fragment reads assume identity layout.
// The swizzle permutes WHICH 16B chunk of the row each thread copies, and writes it
// to the SAME swizzled position it read from -- net effect: element (row, col) lands
// at Ksh[row*72 + col] only if write col == read col. Both use `sw`, so data is
// correct (thread copies global chunk sw -> LDS chunk sw; the permutation is over
// threads, not data). Fragment reads are therefore valid.

// ---------------- GEMM 2: out = attno * Wo^T + bo (f32 out) ----------------
__global__ __launch_bounds__(256, 2) void gemm_out(
    const short* __restrict__ Ab, const short* __restrict__ Wob,
    const float* __restrict__ bo, float* __restrict__ out) {
  __shared__ short Ash[128 * 32];
  __shared__ short Bsh[128 * 32];
  const int tid = threadIdx.x;
  const int wid = tid >> 6, lane = tid & 63;
  const int g = lane >> 4, c = lane & 15;
  const int wm = wid >> 1, wn = wid & 1;
  const int m0 = blockIdx.y * 128, n0 = blockIdx.x * 128;

  f32x4 acc[4][4];
  for (int i = 0; i < 4; i++)
    for (int j = 0; j < 4; j++) acc[i][j] = (f32x4){0.f, 0.f, 0.f, 0.f};

  const int srow = lane >> 2;
  const int scol = (lane & 3) * 8;
  const short* AgL = Ab + (long)(m0 + wid * 32 + srow) * 1024 + scol;
  const short* BgL = Wob + (long)(n0 + wid * 32 + srow) * 1024 + scol;
  short* As0 = &Ash[(wid * 32) * 32];
  short* As1 = &Ash[(wid * 32 + 16) * 32];
  short* Bs0 = &Bsh[(wid * 32) * 32];
  short* Bs1 = &Bsh[(wid * 32 + 16) * 32];

  for (int kt = 0; kt < 32; ++kt) {
    const int ko = kt * 32;
    GLD_LDS16(AgL + ko, As0);
    GLD_LDS16(AgL + ko + 16 * 1024, As1);
    GLD_LDS16(BgL + ko, Bs0);
    GLD_LDS16(BgL + ko + 16 * 1024, Bs1);
    __syncthreads();
    bf16x8 af[4], bfr[4];
    for (int i = 0; i < 4; i++)
      af[i] = *(const bf16x8*)&Ash[(wm * 64 + i * 16 + c) * 32 + g * 8];
    for (int j = 0; j < 4; j++)
      bfr[j] = *(const bf16x8*)&Bsh[(wn * 64 + j * 16 + c) * 32 + g * 8];
    for (int i = 0; i < 4; i++)
      for (int j = 0; j < 4; j++)
        acc[i][j] = __builtin_amdgcn_mfma_f32_16x16x32_bf16(af[i], bfr[j], acc[i][j], 0, 0, 0);
    __syncthreads();
  }

  for (int jt = 0; jt < 4; jt++) {
    const int j = n0 + wn * 64 + jt * 16 + c;
    const float bias = bo[j];
    for (int i = 0; i < 4; i++) {
      const int rbase = m0 + wm * 64 + i * 16 + g * 4;
      for (int reg = 0; reg < 4; reg++)
        out[(long)(rbase + reg) * 1024 + j] = acc[i][jt][reg] + bias;
    }
  }
}

// ---------------- launcher ----------------
extern "C" void kernel_launch(void* const* d_in, const int* in_sizes, int n_in,
                              void* d_out, int out_size, void* d_ws, size_t ws_size,
                              hipStream_t stream) {
  const float* hs = (const float*)d_in[0];
  const float* rpe = (const float*)d_in[1];
  const int* amask = (const int*)d_in[2];
  const float* Wqkv = (const float*)d_in[3];
  const float* bqkv = (const float*)d_in[4];
  const float* Wo = (const float*)d_in[5];
  const float* bo = (const float*)d_in[6];
  float* out = (float*)d_out;

  char* ws = (char*)d_ws;
  auto alloc = [&](size_t bytes) {
    char* p = ws;
    ws += (bytes + 255) & ~(size_t)255;
    return p;
  };
  short* Xb = (short*)alloc(8192LL * 1024 * 2);
  short* Wqkvb = (short*)alloc(3072LL * 1024 * 2);
  short* Wob = (short*)alloc(1024LL * 1024 * 2);
  float* cosT = (float*)alloc(1024 * 32 * 4);
  float* sinT = (float*)alloc(1024 * 32 * 4);
  u64* maskb = (u64*)alloc(8LL * 1024 * 16 * 8);
  short* qb = (short*)alloc(128LL * 1024 * 64 * 2);
  short* kbuf = (short*)alloc(128LL * 1024 * 64 * 2);
  short* vbuf = (short*)alloc(128LL * 1024 * 64 * 2);
  short* vTb = (short*)alloc(128LL * 1024 * 64 * 2);
  short* attno = (short*)alloc(8192LL * 1024 * 2);

  cvt_f32_bf16<<<8192 * 1024 / 4 / 256, 256, 0, stream>>>(hs, Xb, 8192 * 1024);
  cvt_f32_bf16<<<3072 * 1024 / 4 / 256, 256, 0, stream>>>(Wqkv, Wqkvb, 3072 * 1024);
  cvt_f32_bf16<<<1024 * 1024 / 4 / 256, 256, 0, stream>>>(Wo, Wob, 1024 * 1024);
  rope_tables<<<128, 256, 0, stream>>>(rpe, cosT, sinT);
  mask_pack<<<32768, 256, 0, stream>>>(amask, maskb);
  gemm_qkv<<<dim3(24, 64), 256, 0, stream>>>(Xb, Wqkvb, bqkv, cosT, sinT, qb, kbuf, vbuf);
  transpose_v<<<dim3(16, 128), 256, 0, stream>>>(vbuf, vTb);
  flash_attn<<<dim3(16, 128), 256, 0, stream>>>(qb, kbuf, vTb, maskb, attno);
  gemm_out<<<dim3(8, 64), 256, 0, stream>>>(attno, Wob, bo, out);
}

// Round 2
// 365.167 us; speedup vs baseline: 1.0709x; 1.0709x over previous
//
#include <hip/hip_runtime.h>
#include <hip/hip_bf16.h>

typedef short bf16x8 __attribute__((ext_vector_type(8)));
typedef short bf16x4 __attribute__((ext_vector_type(4)));
typedef float f32x4 __attribute__((ext_vector_type(4)));
typedef unsigned int u32;
typedef unsigned long long u64;

#define GLD_LDS16(gp, lp) \
  __builtin_amdgcn_global_load_lds((const __attribute__((address_space(1))) u32*)(gp), \
                                   (__attribute__((address_space(3))) u32*)(lp), 16, 0, 0)

__device__ __forceinline__ short f2bf(float f) {
  u32 u = __builtin_bit_cast(u32, f);
  u = (u + 0x7fffu + ((u >> 16) & 1u)) >> 16;
  return (short)u;
}

// K=16 bf16 MFMA: A,B = 4 bf16 (2 VGPRs). Name differs across ROCm versions.
__device__ __forceinline__ f32x4 mfma_16x16x16_bf16(bf16x4 a, bf16x4 b, f32x4 c) {
#if __has_builtin(__builtin_amdgcn_mfma_f32_16x16x16_bf16)
  return __builtin_amdgcn_mfma_f32_16x16x16_bf16(a, b, c, 0, 0, 0);
#elif __has_builtin(__builtin_amdgcn_mfma_f32_16x16x16bf16_1k)
  return __builtin_amdgcn_mfma_f32_16x16x16bf16_1k(a, b, c, 0, 0, 0);
#else
  f32x4 d = c;
  __asm__ volatile("v_mfma_f32_16x16x16_bf16 %0, %1, %2, %0\n\ts_nop 7\n\ts_nop 7"
                   : "+v"(d) : "v"(a), "v"(b));
  return d;
#endif
}

// ---------------- small prep kernels ----------------

__global__ void cvt_f32_bf16(const float* __restrict__ in, short* __restrict__ out, int n4) {
  int i = (blockIdx.x * 256 + threadIdx.x) * 4;
  float4 v = *(const float4*)(in + i);
  short4 o;
  o.x = f2bf(v.x); o.y = f2bf(v.y); o.z = f2bf(v.z); o.w = f2bf(v.w);
  *(short4*)(out + i) = o;
}

__global__ void rope_tables(const float* __restrict__ rpe, float* __restrict__ cosT,
                            float* __restrict__ sinT) {
  int i = blockIdx.x * 256 + threadIdx.x;  // 32768 = 1024*32
  float v = rpe[i];
  cosT[i] = cosf(v);
  sinT[i] = sinf(v);
}

__global__ void mask_pack(const int* __restrict__ m, u64* __restrict__ out) {
  int i = blockIdx.x * 256 + threadIdx.x;  // 8*1024*1024 threads
  u64 bm = __ballot(m[i] != 0);
  if ((threadIdx.x & 63) == 0) out[i >> 6] = bm;
}

// ---------------- GEMM 1: QKV projection + bias + RoPE + scatter ----------------
// X (8192,1024) bf16, W (3072,1024) bf16; C = X * W^T. Tile 128x128, BK=32.
__global__ __launch_bounds__(256, 2) void gemm_qkv(
    const short* __restrict__ Xb, const short* __restrict__ Wb,
    const float* __restrict__ bqkv, const float* __restrict__ cosT,
    const float* __restrict__ sinT, short* __restrict__ qb,
    short* __restrict__ kbuf, short* __restrict__ vbuf) {
  __shared__ short Ash[128 * 32];
  __shared__ short Bsh[128 * 32];
  const int tid = threadIdx.x;
  const int wid = tid >> 6, lane = tid & 63;
  const int g = lane >> 4, c = lane & 15;
  const int wm = wid >> 1, wn = wid & 1;
  const int m0 = blockIdx.y * 128, n0 = blockIdx.x * 128;

  f32x4 acc[4][4];
  for (int i = 0; i < 4; i++)
    for (int j = 0; j < 4; j++) acc[i][j] = (f32x4){0.f, 0.f, 0.f, 0.f};

  const int srow = lane >> 2;
  const int scol = (lane & 3) * 8;
  const short* AgL = Xb + (long)(m0 + wid * 32 + srow) * 1024 + scol;
  const short* BgL = Wb + (long)(n0 + wid * 32 + srow) * 1024 + scol;
  short* As0 = &Ash[(wid * 32) * 32];
  short* As1 = &Ash[(wid * 32 + 16) * 32];
  short* Bs0 = &Bsh[(wid * 32) * 32];
  short* Bs1 = &Bsh[(wid * 32 + 16) * 32];

  for (int kt = 0; kt < 32; ++kt) {
    const int ko = kt * 32;
    GLD_LDS16(AgL + ko, As0);
    GLD_LDS16(AgL + ko + 16 * 1024, As1);
    GLD_LDS16(BgL + ko, Bs0);
    GLD_LDS16(BgL + ko + 16 * 1024, Bs1);
    __syncthreads();
    bf16x8 af[4], bfr[4];
    for (int i = 0; i < 4; i++)
      af[i] = *(const bf16x8*)&Ash[(wm * 64 + i * 16 + c) * 32 + g * 8];
    for (int j = 0; j < 4; j++)
      bfr[j] = *(const bf16x8*)&Bsh[(wn * 64 + j * 16 + c) * 32 + g * 8];
    for (int i = 0; i < 4; i++)
      for (int j = 0; j < 4; j++)
        acc[i][j] = __builtin_amdgcn_mfma_f32_16x16x32_bf16(af[i], bfr[j], acc[i][j], 0, 0, 0);
    __syncthreads();
  }

  // epilogue: bias, RoPE (q,k), scatter to (B,H,L,D); q pre-scaled by 0.125
  for (int jt = 0; jt < 4; jt++) {
    const int j = n0 + wn * 64 + jt * 16 + c;
    const int three = j >> 10;
    const int hh = (j >> 6) & 15;
    const int d = j & 63;
    const float bias = bqkv[j];
    for (int i = 0; i < 4; i++) {
      const int rbase = m0 + wm * 64 + i * 16 + g * 4;
      for (int reg = 0; reg < 4; reg++) {
        const int r = rbase + reg;
        const int l = r >> 3, b = r & 7;
        float v = acc[i][jt][reg] + bias;
        if (three == 2) {
          vbuf[((long)(b * 16 + hh) * 1024 + l) * 64 + d] = f2bf(v);
        } else {
          float part = __shfl_xor(v, 1, 64);
          float cs = cosT[l * 32 + (d & 31)];
          float sn = sinT[l * 32 + (d & 31)];
          float res = v * cs + ((d & 1) ? part : -part) * sn;
          if (three == 0) res *= 0.125f;  // fold 1/sqrt(D) into q
          short* dst = (three == 0) ? qb : kbuf;
          dst[((long)(b * 16 + hh) * 1024 + l) * 64 + d] = f2bf(res);
        }
      }
    }
  }
}

// ---------------- V transpose: (B,H,L,D) -> (B,H,D,L) ----------------
__global__ __launch_bounds__(256) void transpose_v(const short* __restrict__ vbuf,
                                                   short* __restrict__ vTb) {
  __shared__ short T[64 * 72];
  const int bh = blockIdx.y;
  const int l0 = blockIdx.x * 64;
  const int t = threadIdx.x;
  const int row = t >> 3;
  const int cc = (t & 7) * 8;
  const short* src = vbuf + ((long)bh * 1024 + l0) * 64;
  for (int p = 0; p < 2; p++) {
    int lr = row + p * 32;
    *(bf16x8*)&T[lr * 72 + cc] = *(const bf16x8*)&src[(long)lr * 64 + cc];
  }
  __syncthreads();
  short* dst = vTb + (long)bh * 64 * 1024 + l0;
  for (int p = 0; p < 2; p++) {
    int d = row + p * 32;
    bf16x8 v;
    for (int j = 0; j < 8; j++) v[j] = T[(cc + j) * 72 + d];
    *(bf16x8*)&dst[(long)d * 1024 + cc] = v;
  }
}

// ---------------- flash attention (S^T formulation, register-resident P) ----------------
// q,k: (BH,1024,64) bf16 (q pre-scaled); vT: (BH,64,1024) bf16; maskb: bits (B,1024,16 u64)
// Per block: 64 q-rows, 4 waves x 16 q each. Per 64-key tile:
//   S^T = K·Q^T (swapped-operand 16x16x32 mfma) -> C-layout: lane owns q-col (lane&15),
//   16 keys at row quad*4+reg across 4 tiles. Softmax reduce = 15 in-lane ops + 2 shfls.
//   C-layout row index == B-operand k index of 16x16x16 mfma -> P feeds PV from registers.
__global__ __launch_bounds__(256, 4) void flash_attn(
    const short* __restrict__ qb, const short* __restrict__ kbuf,
    const short* __restrict__ vTb, const u64* __restrict__ maskb,
    short* __restrict__ attno) {
  __shared__ short Ksh[64 * 72];
  __shared__ short Vsh[64 * 72];
  const int t = threadIdx.x;
  const int wid = t >> 6, lane = t & 63;
  const int g = lane >> 4, c = lane & 15;
  const int q0 = blockIdx.x * 64;
  const int bh = blockIdx.y;
  const int b = bh >> 4;
  const int h = bh & 15;
  const long qoff = (long)bh * 1024 * 64;

  // Q fragment (B-operand of S^T mfma): Q[q=c][d=g*8+j]
  bf16x8 aq0, aq1;
  {
    const short* qrow = qb + qoff + (long)(q0 + wid * 16 + c) * 64;
    aq0 = *(const bf16x8*)(qrow + g * 8);
    aq1 = *(const bf16x8*)(qrow + 32 + g * 8);
  }

  // O^T accumulators: Od[dt] holds O^T[dt*16 + g*4 + reg][q=c]
  f32x4 Od[4];
  for (int i = 0; i < 4; i++) Od[i] = (f32x4){0.f, 0.f, 0.f, 0.f};
  float m_run = -1e30f, l_run = 0.f;

  const u64* mrow = maskb + ((long)b * 1024 + q0 + wid * 16 + c) * 16;
  const short* Kg = kbuf + qoff;
  const short* Vg = vTb + qoff;
  const int srow = t >> 3;
  const int sch = (t & 7) * 8;

  for (int ki = 0; ki < 16; ++ki) {
    const int kt0 = ki * 64;
    u64 mw = mrow[ki];  // issue mask load early
    __syncthreads();
    for (int p = 0; p < 2; p++) {
      int rr = srow + p * 32;
      *(bf16x8*)&Ksh[rr * 72 + sch] = *(const bf16x8*)&Kg[(long)(kt0 + rr) * 64 + sch];
      *(bf16x8*)&Vsh[rr * 72 + sch] = *(const bf16x8*)&Vg[(long)rr * 1024 + kt0 + sch];
    }
    __syncthreads();

    // S^T tiles: z[nt] = S^T[key = nt*16 + g*4 + reg][q = c]
    f32x4 z[4];
    for (int nt = 0; nt < 4; nt++) {
      const short* kr = &Ksh[(nt * 16 + c) * 72 + g * 8];
      bf16x8 bk0 = *(const bf16x8*)kr;
      bf16x8 bk1 = *(const bf16x8*)(kr + 32);
      f32x4 zz = (f32x4){0.f, 0.f, 0.f, 0.f};
      zz = __builtin_amdgcn_mfma_f32_16x16x32_bf16(bk0, aq0, zz, 0, 0, 0);
      zz = __builtin_amdgcn_mfma_f32_16x16x32_bf16(bk1, aq1, zz, 0, 0, 0);
      z[nt] = zz;
    }

    // column max over all 64 keys (masked scores included: softmax is shift-invariant,
    // scores are O(2) so no underflow; masked p are zeroed below)
    float mx = fmaxf(fmaxf(z[0][0], z[0][1]), fmaxf(z[0][2], z[0][3]));
    for (int nt = 1; nt < 4; nt++)
      mx = fmaxf(mx, fmaxf(fmaxf(z[nt][0], z[nt][1]), fmaxf(z[nt][2], z[nt][3])));
    mx = fmaxf(mx, __shfl_xor(mx, 16, 64));
    mx = fmaxf(mx, __shfl_xor(mx, 32, 64));
    float mnew = fmaxf(m_run, mx);
    float al = __expf(m_run - mnew);
    m_run = mnew;

    // p = exp(s - mnew), masked -> 0; pack to bf16 B-operands
    bf16x4 pb[4];
    float rs = 0.f;
    for (int nt = 0; nt < 4; nt++) {
      u32 m4 = (u32)(mw >> (nt * 16 + g * 4)) & 0xFu;
      float p0 = (m4 & 1u) ? __expf(z[nt][0] - mnew) : 0.f;
      float p1 = (m4 & 2u) ? __expf(z[nt][1] - mnew) : 0.f;
      float p2 = (m4 & 4u) ? __expf(z[nt][2] - mnew) : 0.f;
      float p3 = (m4 & 8u) ? __expf(z[nt][3] - mnew) : 0.f;
      rs += (p0 + p1) + (p2 + p3);
      union { bf16x4 v; u32 u[2]; } pu;
      pu.u[0] = (u32)(unsigned short)f2bf(p0) | ((u32)(unsigned short)f2bf(p1) << 16);
      pu.u[1] = (u32)(unsigned short)f2bf(p2) | ((u32)(unsigned short)f2bf(p3) << 16);
      pb[nt] = pu.v;
    }
    rs += __shfl_xor(rs, 16, 64);
    rs += __shfl_xor(rs, 32, 64);
    l_run = l_run * al + rs;

    // rescale O and accumulate PV: O^T += V^T_tile · P^T_tile
    for (int dt = 0; dt < 4; dt++) {
      Od[dt][0] *= al; Od[dt][1] *= al; Od[dt][2] *= al; Od[dt][3] *= al;
    }
    for (int nt = 0; nt < 4; nt++) {
      for (int dt = 0; dt < 4; dt++) {
        bf16x4 av = *(const bf16x4*)&Vsh[(dt * 16 + c) * 72 + nt * 16 + g * 4];
        Od[dt] = mfma_16x16x16_bf16(av, pb[nt], Od[dt]);
      }
    }
  }

  // epilogue: normalize, write attno in (L,B,C) layout. Lane owns q-row q0+wid*16+c,
  // d = dt*16 + g*4 + reg -> 4x 8B stores per lane.
  float inv = 1.f / l_run;
  long rbase = ((long)(q0 + wid * 16 + c) * 8 + b) * 1024 + h * 64 + g * 4;
  for (int dt = 0; dt < 4; dt++) {
    bf16x4 o;
    o[0] = f2bf(Od[dt][0] * inv);
    o[1] = f2bf(Od[dt][1] * inv);
    o[2] = f2bf(Od[dt][2] * inv);
    o[3] = f2bf(Od[dt][3] * inv);
    *(bf16x4*)&attno[rbase + dt * 16] = o;
  }
}

// ---------------- GEMM 2: out = attno * Wo^T + bo (f32 out) ----------------
__global__ __launch_bounds__(256, 2) void gemm_out(
    const short* __restrict__ Ab, const short* __restrict__ Wob,
    const float* __restrict__ bo, float* __restrict__ out) {
  __shared__ short Ash[128 * 32];
  __shared__ short Bsh[128 * 32];
  const int tid = threadIdx.x;
  const int wid = tid >> 6, lane = tid & 63;
  const int g = lane >> 4, c = lane & 15;
  const int wm = wid >> 1, wn = wid & 1;
  const int m0 = blockIdx.y * 128, n0 = blockIdx.x * 128;

  f32x4 acc[4][4];
  for (int i = 0; i < 4; i++)
    for (int j = 0; j < 4; j++) acc[i][j] = (f32x4){0.f, 0.f, 0.f, 0.f};

  const int srow = lane >> 2;
  const int scol = (lane & 3) * 8;
  const short* AgL = Ab + (long)(m0 + wid * 32 + srow) * 1024 + scol;
  const short* BgL = Wob + (long)(n0 + wid * 32 + srow) * 1024 + scol;
  short* As0 = &Ash[(wid * 32) * 32];
  short* As1 = &Ash[(wid * 32 + 16) * 32];
  short* Bs0 = &Bsh[(wid * 32) * 32];
  short* Bs1 = &Bsh[(wid * 32 + 16) * 32];

  for (int kt = 0; kt < 32; ++kt) {
    const int ko = kt * 32;
    GLD_LDS16(AgL + ko, As0);
    GLD_LDS16(AgL + ko + 16 * 1024, As1);
    GLD_LDS16(BgL + ko, Bs0);
    GLD_LDS16(BgL + ko + 16 * 1024, Bs1);
    __syncthreads();
    bf16x8 af[4], bfr[4];
    for (int i = 0; i < 4; i++)
      af[i] = *(const bf16x8*)&Ash[(wm * 64 + i * 16 + c) * 32 + g * 8];
    for (int j = 0; j < 4; j++)
      bfr[j] = *(const bf16x8*)&Bsh[(wn * 64 + j * 16 + c) * 32 + g * 8];
    for (int i = 0; i < 4; i++)
      for (int j = 0; j < 4; j++)
        acc[i][j] = __builtin_amdgcn_mfma_f32_16x16x32_bf16(af[i], bfr[j], acc[i][j], 0, 0, 0);
    __syncthreads();
  }

  for (int jt = 0; jt < 4; jt++) {
    const int j = n0 + wn * 64 + jt * 16 + c;
    const float bias = bo[j];
    for (int i = 0; i < 4; i++) {
      const int rbase = m0 + wm * 64 + i * 16 + g * 4;
      for (int reg = 0; reg < 4; reg++)
        out[(long)(rbase + reg) * 1024 + j] = acc[i][jt][reg] + bias;
    }
  }
}

// ---------------- launcher ----------------
extern "C" void kernel_launch(void* const* d_in, const int* in_sizes, int n_in,
                              void* d_out, int out_size, void* d_ws, size_t ws_size,
                              hipStream_t stream) {
  const float* hs = (const float*)d_in[0];
  const float* rpe = (const float*)d_in[1];
  const int* amask = (const int*)d_in[2];
  const float* Wqkv = (const float*)d_in[3];
  const float* bqkv = (const float*)d_in[4];
  const float* Wo = (const float*)d_in[5];
  const float* bo = (const float*)d_in[6];
  float* out = (float*)d_out;

  char* ws = (char*)d_ws;
  auto alloc = [&](size_t bytes) {
    char* p = ws;
    ws += (bytes + 255) & ~(size_t)255;
    return p;
  };
  short* Xb = (short*)alloc(8192LL * 1024 * 2);
  short* Wqkvb = (short*)alloc(3072LL * 1024 * 2);
  short* Wob = (short*)alloc(1024LL * 1024 * 2);
  float* cosT = (float*)alloc(1024 * 32 * 4);
  float* sinT = (float*)alloc(1024 * 32 * 4);
  u64* maskb = (u64*)alloc(8LL * 1024 * 16 * 8);
  short* qb = (short*)alloc(128LL * 1024 * 64 * 2);
  short* kbuf = (short*)alloc(128LL * 1024 * 64 * 2);
  short* vbuf = (short*)alloc(128LL * 1024 * 64 * 2);
  short* vTb = (short*)alloc(128LL * 1024 * 64 * 2);
  short* attno = (short*)alloc(8192LL * 1024 * 2);

  cvt_f32_bf16<<<8192 * 1024 / 4 / 256, 256, 0, stream>>>(hs, Xb, 8192 * 1024);
  cvt_f32_bf16<<<3072 * 1024 / 4 / 256, 256, 0, stream>>>(Wqkv, Wqkvb, 3072 * 1024);
  cvt_f32_bf16<<<1024 * 1024 / 4 / 256, 256, 0, stream>>>(Wo, Wob, 1024 * 1024);
  rope_tables<<<128, 256, 0, stream>>>(rpe, cosT, sinT);
  mask_pack<<<32768, 256, 0, stream>>>(amask, maskb);
  gemm_qkv<<<dim3(24, 64), 256, 0, stream>>>(Xb, Wqkvb, bqkv, cosT, sinT, qb, kbuf, vbuf);
  transpose_v<<<dim3(16, 128), 256, 0, stream>>>(vbuf, vTb);
  flash_attn<<<dim3(16, 128), 256, 0, stream>>>(qb, kbuf, vTb, maskb, attno);
  gemm_out<<<dim3(8, 64), 256, 0, stream>>>(attno, Wob, bo, out);
}

// Round 3
// 349.377 us; speedup vs baseline: 1.1193x; 1.0452x over previous
//
#include <hip/hip_runtime.h>
#include <hip/hip_bf16.h>

typedef short bf16x8 __attribute__((ext_vector_type(8)));
typedef short bf16x4 __attribute__((ext_vector_type(4)));
typedef float f32x4 __attribute__((ext_vector_type(4)));
typedef unsigned int u32;
typedef unsigned long long u64;

#define GLD_LDS16(gp, lp) \
  __builtin_amdgcn_global_load_lds((const __attribute__((address_space(1))) u32*)(gp), \
                                   (__attribute__((address_space(3))) u32*)(lp), 16, 0, 0)

__device__ __forceinline__ short f2bf(float f) {
  u32 u = __builtin_bit_cast(u32, f);
  u = (u + 0x7fffu + ((u >> 16) & 1u)) >> 16;
  return (short)u;
}

// gfx950 hardware packed f32->bf16 (v_cvt_pk_bf16_f32); fallback to manual RNE.
__device__ __forceinline__ u32 pack2_bf16(float a, float b) {
#if __has_builtin(__builtin_amdgcn_cvt_pk_bf16_f32)
  typedef __bf16 bf16v2 __attribute__((ext_vector_type(2)));
  bf16v2 r = __builtin_amdgcn_cvt_pk_bf16_f32(a, b);
  return __builtin_bit_cast(u32, r);
#else
  return (u32)(unsigned short)f2bf(a) | ((u32)(unsigned short)f2bf(b) << 16);
#endif
}

__device__ __forceinline__ float exp2_fast(float x) {
#if __has_builtin(__builtin_amdgcn_exp2f)
  return __builtin_amdgcn_exp2f(x);
#else
  return exp2f(x);
#endif
}

// K=16 bf16 MFMA: A,B = 4 bf16 (2 VGPRs).
__device__ __forceinline__ f32x4 mfma_16x16x16_bf16(bf16x4 a, bf16x4 b, f32x4 c) {
#if __has_builtin(__builtin_amdgcn_mfma_f32_16x16x16_bf16)
  return __builtin_amdgcn_mfma_f32_16x16x16_bf16(a, b, c, 0, 0, 0);
#elif __has_builtin(__builtin_amdgcn_mfma_f32_16x16x16bf16_1k)
  return __builtin_amdgcn_mfma_f32_16x16x16bf16_1k(a, b, c, 0, 0, 0);
#else
  f32x4 d = c;
  __asm__ volatile("v_mfma_f32_16x16x16_bf16 %0, %1, %2, %0\n\ts_nop 7\n\ts_nop 7"
                   : "+v"(d) : "v"(a), "v"(b));
  return d;
#endif
}

// ---------------- small prep kernels ----------------

__global__ void cvt_f32_bf16(const float* __restrict__ in, short* __restrict__ out, int n4) {
  int i = (blockIdx.x * 256 + threadIdx.x) * 4;
  float4 v = *(const float4*)(in + i);
  short4 o;
  o.x = f2bf(v.x); o.y = f2bf(v.y); o.z = f2bf(v.z); o.w = f2bf(v.w);
  *(short4*)(out + i) = o;
}

__global__ void rope_tables(const float* __restrict__ rpe, float* __restrict__ cosT,
                            float* __restrict__ sinT) {
  int i = blockIdx.x * 256 + threadIdx.x;  // 32768 = 1024*32
  float v = rpe[i];
  cosT[i] = cosf(v);
  sinT[i] = sinf(v);
}

__global__ void mask_pack(const int* __restrict__ m, u64* __restrict__ out) {
  int i = blockIdx.x * 256 + threadIdx.x;  // 8*1024*1024 threads
  u64 bm = __ballot(m[i] != 0);
  if ((threadIdx.x & 63) == 0) out[i >> 6] = bm;
}

// ---------------- GEMM 1: QKV projection + bias + RoPE + scatter ----------------
// X (8192,1024) bf16, W (3072,1024) bf16; C = X * W^T. Tile 128x128, BK=32.
// q is pre-scaled by 0.125 * log2(e) so flash softmax can run in exp2 domain.
__global__ __launch_bounds__(256, 2) void gemm_qkv(
    const short* __restrict__ Xb, const short* __restrict__ Wb,
    const float* __restrict__ bqkv, const float* __restrict__ cosT,
    const float* __restrict__ sinT, short* __restrict__ qb,
    short* __restrict__ kbuf, short* __restrict__ vbuf) {
  __shared__ short Ash[128 * 32];
  __shared__ short Bsh[128 * 32];
  const int tid = threadIdx.x;
  const int wid = tid >> 6, lane = tid & 63;
  const int g = lane >> 4, c = lane & 15;
  const int wm = wid >> 1, wn = wid & 1;
  const int m0 = blockIdx.y * 128, n0 = blockIdx.x * 128;

  f32x4 acc[4][4];
  for (int i = 0; i < 4; i++)
    for (int j = 0; j < 4; j++) acc[i][j] = (f32x4){0.f, 0.f, 0.f, 0.f};

  const int srow = lane >> 2;
  const int scol = (lane & 3) * 8;
  const short* AgL = Xb + (long)(m0 + wid * 32 + srow) * 1024 + scol;
  const short* BgL = Wb + (long)(n0 + wid * 32 + srow) * 1024 + scol;
  short* As0 = &Ash[(wid * 32) * 32];
  short* As1 = &Ash[(wid * 32 + 16) * 32];
  short* Bs0 = &Bsh[(wid * 32) * 32];
  short* Bs1 = &Bsh[(wid * 32 + 16) * 32];

  for (int kt = 0; kt < 32; ++kt) {
    const int ko = kt * 32;
    GLD_LDS16(AgL + ko, As0);
    GLD_LDS16(AgL + ko + 16 * 1024, As1);
    GLD_LDS16(BgL + ko, Bs0);
    GLD_LDS16(BgL + ko + 16 * 1024, Bs1);
    __syncthreads();
    bf16x8 af[4], bfr[4];
    for (int i = 0; i < 4; i++)
      af[i] = *(const bf16x8*)&Ash[(wm * 64 + i * 16 + c) * 32 + g * 8];
    for (int j = 0; j < 4; j++)
      bfr[j] = *(const bf16x8*)&Bsh[(wn * 64 + j * 16 + c) * 32 + g * 8];
    for (int i = 0; i < 4; i++)
      for (int j = 0; j < 4; j++)
        acc[i][j] = __builtin_amdgcn_mfma_f32_16x16x32_bf16(af[i], bfr[j], acc[i][j], 0, 0, 0);
    __syncthreads();
  }

  // epilogue: bias, RoPE (q,k), scatter to (B,H,L,D)
  for (int jt = 0; jt < 4; jt++) {
    const int j = n0 + wn * 64 + jt * 16 + c;
    const int three = j >> 10;
    const int hh = (j >> 6) & 15;
    const int d = j & 63;
    const float bias = bqkv[j];
    for (int i = 0; i < 4; i++) {
      const int rbase = m0 + wm * 64 + i * 16 + g * 4;
      for (int reg = 0; reg < 4; reg++) {
        const int r = rbase + reg;
        const int l = r >> 3, b = r & 7;
        float v = acc[i][jt][reg] + bias;
        if (three == 2) {
          vbuf[((long)(b * 16 + hh) * 1024 + l) * 64 + d] = f2bf(v);
        } else {
          float part = __shfl_xor(v, 1, 64);
          float cs = cosT[l * 32 + (d & 31)];
          float sn = sinT[l * 32 + (d & 31)];
          float res = v * cs + ((d & 1) ? part : -part) * sn;
          if (three == 0) res *= 0.18033688011f;  // 1/sqrt(D) * log2(e)
          short* dst = (three == 0) ? qb : kbuf;
          dst[((long)(b * 16 + hh) * 1024 + l) * 64 + d] = f2bf(res);
        }
      }
    }
  }
}

// ---------------- V transpose: (B,H,L,D) -> (B,H,D,L) ----------------
__global__ __launch_bounds__(256) void transpose_v(const short* __restrict__ vbuf,
                                                   short* __restrict__ vTb) {
  __shared__ short T[64 * 72];
  const int bh = blockIdx.y;
  const int l0 = blockIdx.x * 64;
  const int t = threadIdx.x;
  const int row = t >> 3;
  const int cc = (t & 7) * 8;
  const short* src = vbuf + ((long)bh * 1024 + l0) * 64;
  for (int p = 0; p < 2; p++) {
    int lr = row + p * 32;
    *(bf16x8*)&T[lr * 72 + cc] = *(const bf16x8*)&src[(long)lr * 64 + cc];
  }
  __syncthreads();
  short* dst = vTb + (long)bh * 64 * 1024 + l0;
  for (int p = 0; p < 2; p++) {
    int d = row + p * 32;
    bf16x8 v;
    for (int j = 0; j < 8; j++) v[j] = T[(cc + j) * 72 + d];
    *(bf16x8*)&dst[(long)d * 1024 + cc] = v;
  }
}

// ---------------- flash attention v3 ----------------
// S^T formulation, register P, async double-buffered global_load_lds staging.
// LDS layout: unpadded 64-short rows; 16B chunk c stored at position c ^ (row&7)
// (swizzle applied on the GLOBAL address side since DMA fixes LDS dest = base+lane*16).
// q pre-scaled by 0.125*log2e -> softmax in exp2 domain.
__global__ __launch_bounds__(256, 5) void flash_attn(
    const short* __restrict__ qb, const short* __restrict__ kbuf,
    const short* __restrict__ vTb, const u64* __restrict__ maskb,
    short* __restrict__ attno) {
  __shared__ short K0[64 * 64], K1[64 * 64];
  __shared__ short V0[64 * 64], V1[64 * 64];
  const int t = threadIdx.x;
  const int wid = t >> 6, lane = t & 63;
  const int g = lane >> 4, c = lane & 15;
  const int q0 = blockIdx.x * 64;
  const int bh = blockIdx.y;
  const int b = bh >> 4;
  const int h = bh & 15;
  const long qoff = (long)bh * 1024 * 64;

  // Q fragment (B-operand of S^T mfma)
  bf16x8 aq0, aq1;
  {
    const short* qrow = qb + qoff + (long)(q0 + wid * 16 + c) * 64;
    aq0 = *(const bf16x8*)(qrow + g * 8);
    aq1 = *(const bf16x8*)(qrow + 32 + g * 8);
  }

  f32x4 Od[4];
  for (int i = 0; i < 4; i++) Od[i] = (f32x4){0.f, 0.f, 0.f, 0.f};
  float m_run = -1e30f, l_run = 0.f;

  const u64* mrow = maskb + ((long)b * 1024 + q0 + wid * 16 + c) * 16;
  const short* Kg = kbuf + qoff;
  const short* Vg = vTb + qoff;

  // staging: wave w covers rows w*16..w*16+15 (2 issues of 8 rows); lane l fetches
  // data chunk (l&7)^(l>>3) of row w*16+p*8+(l>>3) -> lands at LDS chunk pos l&7.
  const int l8 = lane >> 3, l7 = lane & 7;
  const int sr = wid * 16 + l8;
  const int sch = ((l7 ^ l8) & 7) * 8;

  // fragment read offsets (shorts, within a 64x64 tile buffer)
  const int ck0 = g ^ (c & 7);
  const int kOff0 = c * 64 + ck0 * 8;
  const int kOff1 = c * 64 + (ck0 ^ 4) * 8;
  int vOff[4];
  for (int nt = 0; nt < 4; nt++)
    vOff[nt] = c * 64 + (((2 * nt + (g >> 1)) ^ (c & 7)) * 8) + (g & 1) * 4;

#define STAGE(KD, VD, ktn) do { \
    GLD_LDS16(Kg + (long)((ktn) + sr) * 64 + sch,        &KD[(wid * 16) * 64]); \
    GLD_LDS16(Kg + (long)((ktn) + sr + 8) * 64 + sch,    &KD[(wid * 16 + 8) * 64]); \
    GLD_LDS16(Vg + (long)sr * 1024 + (ktn) + sch,        &VD[(wid * 16) * 64]); \
    GLD_LDS16(Vg + (long)(sr + 8) * 1024 + (ktn) + sch,  &VD[(wid * 16 + 8) * 64]); \
  } while (0)

#define TILE(KB, VB, KP, VP, ki) do { \
    u64 mw = mrow[ki]; \
    __syncthreads(); /* waits this wave's vmcnt(0): buffers KB/VB ready, KP/VP free */ \
    STAGE(KP, VP, (((ki) + 1) & 15) * 64); /* prefetch overlaps compute below */ \
    f32x4 z[4]; \
    for (int nt = 0; nt < 4; nt++) { \
      bf16x8 bk0 = *(const bf16x8*)&KB[kOff0 + nt * 1024]; \
      bf16x8 bk1 = *(const bf16x8*)&KB[kOff1 + nt * 1024]; \
      f32x4 zz = (f32x4){0.f, 0.f, 0.f, 0.f}; \
      zz = __builtin_amdgcn_mfma_f32_16x16x32_bf16(bk0, aq0, zz, 0, 0, 0); \
      zz = __builtin_amdgcn_mfma_f32_16x16x32_bf16(bk1, aq1, zz, 0, 0, 0); \
      z[nt] = zz; \
    } \
    float mx = fmaxf(fmaxf(z[0][0], z[0][1]), fmaxf(z[0][2], z[0][3])); \
    for (int nt = 1; nt < 4; nt++) \
      mx = fmaxf(mx, fmaxf(fmaxf(z[nt][0], z[nt][1]), fmaxf(z[nt][2], z[nt][3]))); \
    mx = fmaxf(mx, __shfl_xor(mx, 16, 64)); \
    mx = fmaxf(mx, __shfl_xor(mx, 32, 64)); \
    float mnew = fmaxf(m_run, mx); \
    if (__ballot(mnew > m_run)) { \
      float al = exp2_fast(m_run - mnew); \
      l_run *= al; \
      for (int dt = 0; dt < 4; dt++) { \
        Od[dt][0] *= al; Od[dt][1] *= al; Od[dt][2] *= al; Od[dt][3] *= al; \
      } \
      m_run = mnew; \
    } \
    bf16x4 pb[4]; \
    float rs = 0.f; \
    for (int nt = 0; nt < 4; nt++) { \
      u32 m4 = (u32)(mw >> (nt * 16 + g * 4)) & 0xFu; \
      float p0 = exp2_fast((m4 & 1u) ? z[nt][0] - mnew : -1000.f); \
      float p1 = exp2_fast((m4 & 2u) ? z[nt][1] - mnew : -1000.f); \
      float p2 = exp2_fast((m4 & 4u) ? z[nt][2] - mnew : -1000.f); \
      float p3 = exp2_fast((m4 & 8u) ? z[nt][3] - mnew : -1000.f); \
      rs += (p0 + p1) + (p2 + p3); \
      union { bf16x4 v; u32 u[2]; } pu; \
      pu.u[0] = pack2_bf16(p0, p1); \
      pu.u[1] = pack2_bf16(p2, p3); \
      pb[nt] = pu.v; \
    } \
    rs += __shfl_xor(rs, 16, 64); \
    rs += __shfl_xor(rs, 32, 64); \
    l_run += rs; \
    for (int nt = 0; nt < 4; nt++) \
      for (int dt = 0; dt < 4; dt++) { \
        bf16x4 av = *(const bf16x4*)&VB[vOff[nt] + dt * 1024]; \
        Od[dt] = mfma_16x16x16_bf16(av, pb[nt], Od[dt]); \
      } \
  } while (0)

  STAGE(K0, V0, 0);
  for (int ki = 0; ki < 16; ki += 2) {
    TILE(K0, V0, K1, V1, ki);
    TILE(K1, V1, K0, V0, ki + 1);
  }
#undef TILE
#undef STAGE

  // epilogue: normalize, write attno in (L,B,C) layout
  float inv = 1.f / l_run;
  long rbase = ((long)(q0 + wid * 16 + c) * 8 + b) * 1024 + h * 64 + g * 4;
  for (int dt = 0; dt < 4; dt++) {
    union { bf16x4 v; u32 u[2]; } o;
    o.u[0] = pack2_bf16(Od[dt][0] * inv, Od[dt][1] * inv);
    o.u[1] = pack2_bf16(Od[dt][2] * inv, Od[dt][3] * inv);
    *(bf16x4*)&attno[rbase + dt * 16] = o.v;
  }
}

// ---------------- GEMM 2: out = attno * Wo^T + bo (f32 out) ----------------
__global__ __launch_bounds__(256, 2) void gemm_out(
    const short* __restrict__ Ab, const short* __restrict__ Wob,
    const float* __restrict__ bo, float* __restrict__ out) {
  __shared__ short Ash[128 * 32];
  __shared__ short Bsh[128 * 32];
  const int tid = threadIdx.x;
  const int wid = tid >> 6, lane = tid & 63;
  const int g = lane >> 4, c = lane & 15;
  const int wm = wid >> 1, wn = wid & 1;
  const int m0 = blockIdx.y * 128, n0 = blockIdx.x * 128;

  f32x4 acc[4][4];
  for (int i = 0; i < 4; i++)
    for (int j = 0; j < 4; j++) acc[i][j] = (f32x4){0.f, 0.f, 0.f, 0.f};

  const int srow = lane >> 2;
  const int scol = (lane & 3) * 8;
  const short* AgL = Ab + (long)(m0 + wid * 32 + srow) * 1024 + scol;
  const short* BgL = Wob + (long)(n0 + wid * 32 + srow) * 1024 + scol;
  short* As0 = &Ash[(wid * 32) * 32];
  short* As1 = &Ash[(wid * 32 + 16) * 32];
  short* Bs0 = &Bsh[(wid * 32) * 32];
  short* Bs1 = &Bsh[(wid * 32 + 16) * 32];

  for (int kt = 0; kt < 32; ++kt) {
    const int ko = kt * 32;
    GLD_LDS16(AgL + ko, As0);
    GLD_LDS16(AgL + ko + 16 * 1024, As1);
    GLD_LDS16(BgL + ko, Bs0);
    GLD_LDS16(BgL + ko + 16 * 1024, Bs1);
    __syncthreads();
    bf16x8 af[4], bfr[4];
    for (int i = 0; i < 4; i++)
      af[i] = *(const bf16x8*)&Ash[(wm * 64 + i * 16 + c) * 32 + g * 8];
    for (int j = 0; j < 4; j++)
      bfr[j] = *(const bf16x8*)&Bsh[(wn * 64 + j * 16 + c) * 32 + g * 8];
    for (int i = 0; i < 4; i++)
      for (int j = 0; j < 4; j++)
        acc[i][j] = __builtin_amdgcn_mfma_f32_16x16x32_bf16(af[i], bfr[j], acc[i][j], 0, 0, 0);
    __syncthreads();
  }

  for (int jt = 0; jt < 4; jt++) {
    const int j = n0 + wn * 64 + jt * 16 + c;
    const float bias = bo[j];
    for (int i = 0; i < 4; i++) {
      const int rbase = m0 + wm * 64 + i * 16 + g * 4;
      for (int reg = 0; reg < 4; reg++)
        out[(long)(rbase + reg) * 1024 + j] = acc[i][jt][reg] + bias;
    }
  }
}

// ---------------- launcher ----------------
extern "C" void kernel_launch(void* const* d_in, const int* in_sizes, int n_in,
                              void* d_out, int out_size, void* d_ws, size_t ws_size,
                              hipStream_t stream) {
  const float* hs = (const float*)d_in[0];
  const float* rpe = (const float*)d_in[1];
  const int* amask = (const int*)d_in[2];
  const float* Wqkv = (const float*)d_in[3];
  const float* bqkv = (const float*)d_in[4];
  const float* Wo = (const float*)d_in[5];
  const float* bo = (const float*)d_in[6];
  float* out = (float*)d_out;

  char* ws = (char*)d_ws;
  auto alloc = [&](size_t bytes) {
    char* p = ws;
    ws += (bytes + 255) & ~(size_t)255;
    return p;
  };
  short* Xb = (short*)alloc(8192LL * 1024 * 2);
  short* Wqkvb = (short*)alloc(3072LL * 1024 * 2);
  short* Wob = (short*)alloc(1024LL * 1024 * 2);
  float* cosT = (float*)alloc(1024 * 32 * 4);
  float* sinT = (float*)alloc(1024 * 32 * 4);
  u64* maskb = (u64*)alloc(8LL * 1024 * 16 * 8);
  short* qb = (short*)alloc(128LL * 1024 * 64 * 2);
  short* kbuf = (short*)alloc(128LL * 1024 * 64 * 2);
  short* vbuf = (short*)alloc(128LL * 1024 * 64 * 2);
  short* vTb = (short*)alloc(128LL * 1024 * 64 * 2);
  short* attno = (short*)alloc(8192LL * 1024 * 2);

  cvt_f32_bf16<<<8192 * 1024 / 4 / 256, 256, 0, stream>>>(hs, Xb, 8192 * 1024);
  cvt_f32_bf16<<<3072 * 1024 / 4 / 256, 256, 0, stream>>>(Wqkv, Wqkvb, 3072 * 1024);
  cvt_f32_bf16<<<1024 * 1024 / 4 / 256, 256, 0, stream>>>(Wo, Wob, 1024 * 1024);
  rope_tables<<<128, 256, 0, stream>>>(rpe, cosT, sinT);
  mask_pack<<<32768, 256, 0, stream>>>(amask, maskb);
  gemm_qkv<<<dim3(24, 64), 256, 0, stream>>>(Xb, Wqkvb, bqkv, cosT, sinT, qb, kbuf, vbuf);
  transpose_v<<<dim3(16, 128), 256, 0, stream>>>(vbuf, vTb);
  flash_attn<<<dim3(16, 128), 256, 0, stream>>>(qb, kbuf, vTb, maskb, attno);
  gemm_out<<<dim3(8, 64), 256, 0, stream>>>(attno, Wob, bo, out);
}